// Round 1
// baseline (14430.692 us; speedup 1.0000x reference)
//
#include <hip/hip_runtime.h>
#include <cstdint>
#include <cstddef>

#define DIM     2048
#define NHEADS  16
#define HDIM    128
#define SEQ     2048
#define HIDDEN  5632
#define VOCAB   32000

typedef _Float16 f16;
typedef __attribute__((ext_vector_type(2))) _Float16 f16x2;
typedef __attribute__((ext_vector_type(4))) _Float16 f16x4;
typedef __attribute__((ext_vector_type(8))) _Float16 f16x8;
typedef __attribute__((ext_vector_type(4))) float floatx4;

// ---------------- embedding gather: h[i][:] = emb[tok[i]][:] (fp32) ----------------
__global__ __launch_bounds__(256) void embed_kernel(const int* __restrict__ tok,
                                                    const float* __restrict__ emb,
                                                    float* __restrict__ h) {
  int i = blockIdx.x;
  int t = tok[i];
  const float4* src = (const float4*)(emb + (size_t)t * DIM);
  float4* dst = (float4*)(h + (size_t)i * DIM);
  for (int c = threadIdx.x; c < DIM / 4; c += 256) dst[c] = src[c];
}

// ---------------- rmsnorm: fp32 h row -> fp16 normed*w ----------------
__global__ __launch_bounds__(256) void rmsnorm_kernel(const float* __restrict__ h,
                                                      const float* __restrict__ w,
                                                      f16* __restrict__ out) {
  int i = blockIdx.x;
  int t = threadIdx.x;
  const float4* row = (const float4*)(h + (size_t)i * DIM);
  float4 a = row[t];
  float4 b = row[t + 256];
  float ss = a.x * a.x + a.y * a.y + a.z * a.z + a.w * a.w +
             b.x * b.x + b.y * b.y + b.z * b.z + b.w * b.w;
#pragma unroll
  for (int o = 1; o < 64; o <<= 1) ss += __shfl_xor(ss, o, 64);
  __shared__ float red[4];
  if ((t & 63) == 0) red[t >> 6] = ss;
  __syncthreads();
  ss = red[0] + red[1] + red[2] + red[3];
  float inv = rsqrtf(ss * (1.0f / DIM) + 1e-6f);
  const float4* wr = (const float4*)w;
  float4 w0 = wr[t], w1 = wr[t + 256];
  f16x4 p0, p1;
  p0.x = (f16)(a.x * inv * w0.x); p0.y = (f16)(a.y * inv * w0.y);
  p0.z = (f16)(a.z * inv * w0.z); p0.w = (f16)(a.w * inv * w0.w);
  p1.x = (f16)(b.x * inv * w1.x); p1.y = (f16)(b.y * inv * w1.y);
  p1.z = (f16)(b.z * inv * w1.z); p1.w = (f16)(b.w * inv * w1.w);
  *(f16x4*)(out + (size_t)i * DIM + t * 4) = p0;
  *(f16x4*)(out + (size_t)i * DIM + (t + 256) * 4) = p1;
}

// ---------------- MFMA GEMM: C[M][N] = A_f16[M][K] @ B_f32->f16[K][N] ----------------
// Tile BM_ x 128, BK=32, 4 waves in 2x2. LDS stride 40 f16 (=20 words): rows r,r+8
// alias -> only 2-way bank conflicts (free). EPI: 0=f16 store, 1=fp32 residual +=,
// 2=fp32 store. Up to 3 fused B/C pairs selected by blockIdx.x / ntx.
template <int BM_, int EPI>
__global__ __launch_bounds__(256) void gemm_kernel(
    const f16* __restrict__ A,
    const float* __restrict__ B0, const float* __restrict__ B1, const float* __restrict__ B2,
    f16* __restrict__ C0, f16* __restrict__ C1, f16* __restrict__ C2,
    float* __restrict__ resF, float* __restrict__ outF,
    int N, int K, int ntx) {
  constexpr int MI = BM_ / 32;
  __shared__ alignas(16) f16 sA[BM_ * 40];
  __shared__ alignas(16) f16 sB[128 * 40];

  int bx = blockIdx.x;
  int g = bx / ntx;
  int bxn = bx - g * ntx;
  const float* Bp = (g == 0) ? B0 : ((g == 1) ? B1 : B2);
  f16* Cp = (g == 0) ? C0 : ((g == 1) ? C1 : C2);
  int n0 = bxn * 128;
  int m0 = blockIdx.y * BM_;
  int tid = threadIdx.x;
  int w = tid >> 6, lane = tid & 63;
  int quad = lane >> 4, l15 = lane & 15;
  int wm = w >> 1, wn = w & 1;

  floatx4 acc[MI][4];
#pragma unroll
  for (int mi = 0; mi < MI; mi++)
#pragma unroll
    for (int ni = 0; ni < 4; ni++) {
      floatx4 z = {0.f, 0.f, 0.f, 0.f};
      acc[mi][ni] = z;
    }

  for (int k0 = 0; k0 < K; k0 += 32) {
    // stage A tile (already fp16): BM_ rows x 32 k, 16B chunks
    for (int c = tid; c < BM_ * 4; c += 256) {
      int row = c >> 2, cc = c & 3;
      uint4 av = *(const uint4*)(A + (size_t)(m0 + row) * K + k0 + cc * 8);
      *(uint4*)&sA[row * 40 + cc * 8] = av;  // (row*40+cc*8)*2 is 16B aligned
    }
    // stage B tile: fp32 -> fp16 convert + transpose to [n][k]
    for (int c = tid; c < 1024; c += 256) {
      int kr = c >> 5, nc = (c & 31) << 2;
      float4 bv = *(const float4*)(Bp + (size_t)(k0 + kr) * N + n0 + nc);
      sB[(nc + 0) * 40 + kr] = (f16)bv.x;
      sB[(nc + 1) * 40 + kr] = (f16)bv.y;
      sB[(nc + 2) * 40 + kr] = (f16)bv.z;
      sB[(nc + 3) * 40 + kr] = (f16)bv.w;
    }
    __syncthreads();
    // fragments: A[m=l15][k=quad*8+j], B[k=quad*8+j][n=l15] -> contiguous b128 reads
    f16x8 af[MI], bf[4];
#pragma unroll
    for (int mi = 0; mi < MI; mi++)
      af[mi] = *(const f16x8*)&sA[(wm * (BM_ / 2) + mi * 16 + l15) * 40 + quad * 8];
#pragma unroll
    for (int ni = 0; ni < 4; ni++)
      bf[ni] = *(const f16x8*)&sB[(wn * 64 + ni * 16 + l15) * 40 + quad * 8];
#pragma unroll
    for (int mi = 0; mi < MI; mi++)
#pragma unroll
      for (int ni = 0; ni < 4; ni++)
        acc[mi][ni] = __builtin_amdgcn_mfma_f32_16x16x32_f16(af[mi], bf[ni], acc[mi][ni], 0, 0, 0);
    __syncthreads();
  }

  // epilogue: D row = quad*4 + r, col = l15 (m89-verified layout)
#pragma unroll
  for (int mi = 0; mi < MI; mi++) {
#pragma unroll
    for (int ni = 0; ni < 4; ni++) {
#pragma unroll
      for (int r = 0; r < 4; r++) {
        int row = m0 + wm * (BM_ / 2) + mi * 16 + quad * 4 + r;
        int col = n0 + wn * 64 + ni * 16 + l15;
        float vv = acc[mi][ni][r];
        if constexpr (EPI == 0) {
          Cp[(size_t)row * N + col] = (f16)vv;
        } else if constexpr (EPI == 1) {
          resF[(size_t)row * N + col] += vv;
        } else {
          outF[(size_t)row * N + col] = vv;
        }
      }
    }
  }
}

// ---------------- RoPE in-place on q and k (fp16) ----------------
__global__ __launch_bounds__(256) void rope_kernel(f16* __restrict__ q, f16* __restrict__ k) {
  int i = blockIdx.x;  // token position
  for (int p = threadIdx.x; p < NHEADS * 64; p += 256) {
    int hh = p >> 6, j = p & 63;
    // inv_freq[j] = 10000^(-j/64) = exp(-j * ln(10000)/64)
    float freq = __expf(-0.14391156831f * (float)j);
    float ang = (float)i * freq;
    float sn, cs;
    sincosf(ang, &sn, &cs);  // accurate range reduction (ang up to 2047 rad)
    size_t base = (size_t)i * DIM + hh * HDIM + j;
    float a0 = (float)q[base], a1 = (float)q[base + 64];
    q[base]      = (f16)(a0 * cs - a1 * sn);
    q[base + 64] = (f16)(a1 * cs + a0 * sn);
    float b0 = (float)k[base], b1 = (float)k[base + 64];
    k[base]      = (f16)(b0 * cs - b1 * sn);
    k[base + 64] = (f16)(b1 * cs + b0 * sn);
  }
}

// ---------------- causal attention, one (head, 8-query-row) block ----------------
// Dynamic LDS: float S[8][2048] = 64 KB score tile. Phase1: scores (VALU dot).
// Phase2: per-wave softmax (rows w and w+4) + PV accumulation, d=2*lane..+1.
__global__ __launch_bounds__(256) void attn_kernel(const f16* __restrict__ q,
                                                   const f16* __restrict__ k,
                                                   const f16* __restrict__ v,
                                                   f16* __restrict__ o) {
  extern __shared__ float S[];
  int q0 = blockIdx.x * 8;
  int head = blockIdx.y;
  const float scale = 0.08838834764831845f;  // 1/sqrt(128)
  int tid = threadIdx.x;

  {  // phase 1: thread (r = tid>>5, c = tid&31) computes S[r][j] for j = c mod 32
    int r = tid >> 5, c = tid & 31;
    int gi = q0 + r;
    int jmask = gi + 1;
    const f16* qrow = q + (size_t)gi * DIM + head * HDIM;
    float qreg[HDIM];
#pragma unroll
    for (int d = 0; d < HDIM; d += 8) {
      f16x8 qv = *(const f16x8*)(qrow + d);
#pragma unroll
      for (int u = 0; u < 8; u++) qreg[d + u] = (float)qv[u];
    }
    for (int j = c; j < q0 + 8; j += 32) {
      const f16* krow = k + (size_t)j * DIM + head * HDIM;
      float acc = 0.f;
#pragma unroll
      for (int d = 0; d < HDIM; d += 8) {
        f16x8 kv = *(const f16x8*)(krow + d);
#pragma unroll
        for (int u = 0; u < 8; u++) acc += qreg[d + u] * (float)kv[u];
      }
      S[r * SEQ + j] = (j < jmask) ? acc * scale : -1e30f;
    }
  }
  __syncthreads();

  int w = tid >> 6, lane = tid & 63;
#pragma unroll
  for (int rr = 0; rr < 2; rr++) {
    int r = w + rr * 4;
    int gi = q0 + r;
    int jn = gi + 1;  // causal: j <= gi
    float* Sr = S + r * SEQ;
    float m = -1e30f;
    for (int j = lane; j < jn; j += 64) m = fmaxf(m, Sr[j]);
#pragma unroll
    for (int o2 = 1; o2 < 64; o2 <<= 1) m = fmaxf(m, __shfl_xor(m, o2, 64));
    float sum = 0.f;
    for (int j = lane; j < jn; j += 64) {
      float e = __expf(Sr[j] - m);
      Sr[j] = e;
      sum += e;
    }
#pragma unroll
    for (int o2 = 1; o2 < 64; o2 <<= 1) sum += __shfl_xor(sum, o2, 64);
    float inv = 1.0f / sum;
    float o0 = 0.f, o1 = 0.f;
    const f16* vp = v + head * HDIM + 2 * lane;
    for (int j = 0; j < jn; j++) {
      float e = Sr[j];  // wave-uniform broadcast read
      f16x2 vv = *(const f16x2*)(vp + (size_t)j * DIM);
      o0 += e * (float)vv.x;
      o1 += e * (float)vv.y;
    }
    f16x2 res;
    res.x = (f16)(o0 * inv);
    res.y = (f16)(o1 * inv);
    *(f16x2*)(o + (size_t)gi * DIM + head * HDIM + 2 * lane) = res;
  }
}

// ---------------- ffn gate: g1 = silu(g1) * g3 ----------------
__global__ __launch_bounds__(256) void silu_kernel(f16* __restrict__ g1, const f16* __restrict__ g3) {
  size_t idx = (size_t)blockIdx.x * 256 + threadIdx.x;
  float a = (float)g1[idx], b = (float)g3[idx];
  float s = a / (1.0f + __expf(-a));
  g1[idx] = (f16)(s * b);
}

extern "C" void kernel_launch(void* const* d_in, const int* in_sizes, int n_in,
                              void* d_out, int out_size, void* d_ws, size_t ws_size,
                              hipStream_t stream) {
  (void)in_sizes; (void)n_in; (void)out_size; (void)ws_size;
  const int*   tokens = (const int*)d_in[0];
  const float* emb    = (const float*)d_in[1];
  const float* wq     = (const float*)d_in[2];
  const float* wk     = (const float*)d_in[3];
  const float* wv     = (const float*)d_in[4];
  const float* wo     = (const float*)d_in[5];
  const float* w1     = (const float*)d_in[6];
  const float* w2     = (const float*)d_in[7];
  const float* w3     = (const float*)d_in[8];
  const float* anw    = (const float*)d_in[9];
  const float* fnw    = (const float*)d_in[10];
  const float* finw   = (const float*)d_in[11];
  const float* outw   = (const float*)d_in[12];
  float* out = (float*)d_out;

  // workspace layout (104 MB total), everything rewritten every call
  char* ws = (char*)d_ws;
  float* h  = (float*)(ws);                               // 16 MB fp32 residual
  f16*   x  = (f16*)(ws + (size_t)16 * 1024 * 1024);      //  8 MB normed acts
  f16*   q  = (f16*)(ws + (size_t)24 * 1024 * 1024);      //  8 MB
  f16*   k  = (f16*)(ws + (size_t)32 * 1024 * 1024);      //  8 MB
  f16*   v  = (f16*)(ws + (size_t)40 * 1024 * 1024);      //  8 MB
  f16*   ao = (f16*)(ws + (size_t)48 * 1024 * 1024);      //  8 MB attn out
  f16*   g1 = (f16*)(ws + (size_t)56 * 1024 * 1024);      // 23 MB
  f16*   g3 = (f16*)(ws + (size_t)80 * 1024 * 1024);      // 23 MB

  embed_kernel<<<SEQ, 256, 0, stream>>>(tokens, emb, h);

  for (int l = 0; l < 4; l++) {
    const float* wq_l = wq + (size_t)l * DIM * DIM;
    const float* wk_l = wk + (size_t)l * DIM * DIM;
    const float* wv_l = wv + (size_t)l * DIM * DIM;
    const float* wo_l = wo + (size_t)l * DIM * DIM;
    const float* w1_l = w1 + (size_t)l * DIM * HIDDEN;
    const float* w2_l = w2 + (size_t)l * HIDDEN * DIM;
    const float* w3_l = w3 + (size_t)l * DIM * HIDDEN;

    rmsnorm_kernel<<<SEQ, 256, 0, stream>>>(h, anw + l * DIM, x);
    // fused QKV: 3 x (2048x2048x2048)
    gemm_kernel<128, 0><<<dim3(48, 16), 256, 0, stream>>>(
        x, wq_l, wk_l, wv_l, q, k, v, nullptr, nullptr, DIM, DIM, 16);
    rope_kernel<<<SEQ, 256, 0, stream>>>(q, k);
    attn_kernel<<<dim3(SEQ / 8, NHEADS), 256, 65536, stream>>>(q, k, v, ao);
    // h += ao @ wo  (BM=64 -> 512 blocks for occupancy)
    gemm_kernel<64, 1><<<dim3(16, 32), 256, 0, stream>>>(
        ao, wo_l, wo_l, wo_l, nullptr, nullptr, nullptr, h, nullptr, DIM, DIM, 16);
    rmsnorm_kernel<<<SEQ, 256, 0, stream>>>(h, fnw + l * DIM, x);
    // fused W1/W3: 2 x (2048x2048x5632)
    gemm_kernel<128, 0><<<dim3(88, 16), 256, 0, stream>>>(
        x, w1_l, w3_l, w3_l, g1, g3, g3, nullptr, nullptr, HIDDEN, DIM, 44);
    silu_kernel<<<(SEQ * HIDDEN) / 256, 256, 0, stream>>>(g1, g3);
    // h += ffn @ w2
    gemm_kernel<64, 1><<<dim3(16, 32), 256, 0, stream>>>(
        g1, w2_l, w2_l, w2_l, nullptr, nullptr, nullptr, h, nullptr, DIM, HIDDEN, 16);
  }

  rmsnorm_kernel<<<SEQ, 256, 0, stream>>>(h, finw, x);
  // logits: 2048 x 32000 x 2048, fp32 out
  gemm_kernel<128, 2><<<dim3(250, 16), 256, 0, stream>>>(
      x, outw, outw, outw, nullptr, nullptr, nullptr, nullptr, out, VOCAB, DIM, 250);
}